// Round 10
// baseline (789.980 us; speedup 1.0000x reference)
//
#include <hip/hip_runtime.h>

// LSS-FPN round 9: conv3x3 with 64x64-per-wave (4x4 acc) + LDS chunk swizzle;
// 1x1 convs as bf16 MFMA GEMMs from xt layout (fp32 planar path removed).
// Workspace ~38.9 MB.

#define FH_ 16
#define FW_ 44
#define SP_ 704
#define XSTR 960         // xt rows per image (incl. halo slack)
#define NIMG 6
#define CIN 512
#define DCH 112
#define CCTX 80
#define NXY 128
#define NVOX (NXY * NXY)
#define NPTS (NIMG * DCH * SP_)
#define CHUNK 64

#define WROWS 232        // LDS X window rows (128-px tile + 3x3 halo)
#define CIP 40           // padded LDS k-stride in shorts

typedef unsigned short u16;
typedef __attribute__((ext_vector_type(8))) short bf16x8;
typedef __attribute__((ext_vector_type(4))) float f32x4;

__device__ __forceinline__ float bf2f(u16 b) {
    union { unsigned u; float f; } v; v.u = ((unsigned)b) << 16; return v.f;
}
__device__ __forceinline__ u16 f2bf(float f) {
    union { float f; unsigned u; } v; v.f = f;
    unsigned r = v.u + 0x7fffu + ((v.u >> 16) & 1u);   // RTNE
    return (u16)(r >> 16);
}
__device__ __forceinline__ int spad_of(int s) {
    return (s / 44) * 46 + (s % 44) + 47;
}
// swizzled LDS chunk offset (chunk = 8 shorts); breaks row-D8 bank aliasing
__device__ __forceinline__ int swz(int rowco, int chunk) {
    return ((chunk + (rowco >> 3)) & 3) * 8;
}

// ---------------- zero fill ---------------------------------------------------
__global__ void zero_k(float4* __restrict__ p, long n4) {
    long i = (long)blockIdx.x * blockDim.x + threadIdx.x;
    if (i < n4) p[i] = make_float4(0.f, 0.f, 0.f, 0.f);
}

// ---------------- src fp32 [n][ci][704] -> xt bf16 [n][XSTR][512] -------------
__global__ void src_to_xt_k(const float* __restrict__ src, short* __restrict__ xt) {
    int e = blockIdx.x * 256 + threadIdx.x;
    if (e >= NIMG * SP_ * CIN) return;
    int ci = e & 511;
    int r = e >> 9;
    int s = r % SP_, n = r / SP_;
    float v = src[((size_t)n * CIN + ci) * SP_ + s];
    xt[((size_t)n * XSTR + spad_of(s)) * 512 + ci] = (short)f2bf(v);
}

// ---------------- weight hi-split: fp32 [co][ci][9] -> bf16 [t][co][ci] -------
__global__ void wsplit_k(const float* __restrict__ w, short* __restrict__ hi) {
    int e = blockIdx.x * 256 + threadIdx.x;
    if (e >= CIN * CIN) return;
    const float* wp = w + (size_t)e * 9;
#pragma unroll
    for (int t = 0; t < 9; ++t)
        hi[(size_t)t * (CIN * CIN) + e] = (short)f2bf(wp[t]);
}

// 1x1 weights fp32 [co][ci] -> bf16 same order
__global__ void wsplit1_k(const float* __restrict__ w, short* __restrict__ o, int n) {
    int i = blockIdx.x * 256 + threadIdx.x;
    if (i < n) o[i] = (short)f2bf(w[i]);
}

// ---------------- conv3x3+relu via MFMA ---------------------------------------
// grid (6, 8, 6), block 128 = 2 waves; each wave 64sp x 64co, 4x4 acc.
__global__ __launch_bounds__(128, 2) void conv3_k(
    const short* __restrict__ xt, const short* __restrict__ wth,
    short* __restrict__ xout)
{
    __shared__ short Xs[WROWS * CIP];       // 18,560 B
    __shared__ short Wsh[9 * 64 * CIP];     // 46,080 B
    const int tid = threadIdx.x;
    const int s0 = blockIdx.x * 128, co0 = blockIdx.y * 64, n = blockIdx.z;
    const int base = spad_of(s0) - 47;
    const int lane = tid & 63, wave = tid >> 6;
    const int kg = lane >> 4, lrow = lane & 15;

    int sloc[4];
#pragma unroll
    for (int ms = 0; ms < 4; ++ms)
        sloc[ms] = spad_of(s0 + wave * 64 + ms * 16 + lrow) - base;

    const f32x4 zero4 = {0.f, 0.f, 0.f, 0.f};
    f32x4 acc[4][4];
#pragma unroll
    for (int ms = 0; ms < 4; ++ms)
#pragma unroll
        for (int ns = 0; ns < 4; ++ns) acc[ms][ns] = zero4;

    const short* xb = xt + ((size_t)n * XSTR + base) * 512;

    for (int kc = 0; kc < 16; ++kc) {
        __syncthreads();
        // stage X: 232 rows x 4 chunks = 928 tasks (global-coalesced p-inner)
#pragma unroll
        for (int it = 0; it < 8; ++it) {
            int q = it * 128 + tid;
            if (q < WROWS * 4) {
                int row = q >> 2, p = q & 3;
                *(bf16x8*)&Xs[row * CIP + swz(row, p)] =
                    *(const bf16x8*)(xb + (size_t)row * 512 + kc * 32 + p * 8);
            }
        }
        // stage W: 9 taps x 64 co x 4 chunks = 2304 tasks = 18*128 exact
#pragma unroll
        for (int it = 0; it < 18; ++it) {
            int q = it * 128 + tid;
            int t = q >> 8, co = (q >> 2) & 63, p = q & 3;
            *(bf16x8*)&Wsh[(t * 64 + co) * CIP + swz(co, p)] =
                *(const bf16x8*)(wth + ((size_t)t * CIN + co0 + co) * CIN + kc * 32 + p * 8);
        }
        __syncthreads();
        constexpr int OFF[9] = {-47, -46, -45, -1, 0, 1, 45, 46, 47};
#pragma unroll
        for (int t = 0; t < 9; ++t) {
            bf16x8 a[4], b[4];
#pragma unroll
            for (int ms = 0; ms < 4; ++ms) {
                int row = sloc[ms] + OFF[t];
                a[ms] = *(const bf16x8*)&Xs[row * CIP + swz(row, kg)];
            }
#pragma unroll
            for (int ns = 0; ns < 4; ++ns) {
                int co = ns * 16 + lrow;
                b[ns] = *(const bf16x8*)&Wsh[(t * 64 + co) * CIP + swz(co, kg)];
            }
#pragma unroll
            for (int ms = 0; ms < 4; ++ms)
#pragma unroll
                for (int ns = 0; ns < 4; ++ns)
                    acc[ms][ns] = __builtin_amdgcn_mfma_f32_16x16x32_bf16(
                        a[ms], b[ns], acc[ms][ns], 0, 0, 0);
        }
    }
    // epilogue: C row = kg*4+r (spatial), col = lrow (co); relu; bf16 xt write
#pragma unroll
    for (int ms = 0; ms < 4; ++ms)
#pragma unroll
        for (int ns = 0; ns < 4; ++ns)
#pragma unroll
            for (int r = 0; r < 4; ++r) {
                int sg = s0 + wave * 64 + ms * 16 + kg * 4 + r;
                if (sg < SP_) {
                    int co = co0 + ns * 16 + lrow;
                    float v = fmaxf(acc[ms][ns][r], 0.f);
                    xout[((size_t)n * XSTR + spad_of(sg)) * 512 + co] = (short)f2bf(v);
                }
            }
}

// ---------------- 1x1 conv as GEMM: xt bf16 -> fp32 [n][s][NCO] ---------------
// grid (6, 1, 6), block 256 = 4 waves; wave = 32sp x NCO. A direct from global.
template <int NCO>
__global__ __launch_bounds__(256, 2) void gemm1x1_k(
    const short* __restrict__ xtin, const short* __restrict__ wb,
    const float* __restrict__ bias, float* __restrict__ outT)
{
    constexpr int NST = NCO / 16;
    __shared__ short Wb[NCO * CIP];
    const int tid = threadIdx.x;
    const int s0 = blockIdx.x * 128, n = blockIdx.z;
    const int lane = tid & 63, wave = tid >> 6;
    const int kg = lane >> 4, lrow = lane & 15;
    const int swave = s0 + wave * 32;

    int arow[2];
#pragma unroll
    for (int ms = 0; ms < 2; ++ms)
        arow[ms] = spad_of(swave + ms * 16 + lrow);

    const f32x4 zero4 = {0.f, 0.f, 0.f, 0.f};
    f32x4 acc[2][NST];
#pragma unroll
    for (int ms = 0; ms < 2; ++ms)
#pragma unroll
        for (int ns = 0; ns < NST; ++ns) acc[ms][ns] = zero4;

    const short* xb = xtin + (size_t)n * XSTR * 512;

    for (int kc = 0; kc < 16; ++kc) {
        __syncthreads();
#pragma unroll
        for (int it = 0; it < 2; ++it) {
            int q = it * 256 + tid;
            if (q < NCO * 4) {
                int co = q >> 2, p = q & 3;
                *(bf16x8*)&Wb[co * CIP + swz(co, p)] =
                    *(const bf16x8*)(wb + (size_t)co * CIN + kc * 32 + p * 8);
            }
        }
        __syncthreads();
        bf16x8 a[2];
#pragma unroll
        for (int ms = 0; ms < 2; ++ms)
            a[ms] = *(const bf16x8*)(xb + (size_t)arow[ms] * 512 + kc * 32 + kg * 8);
#pragma unroll
        for (int ns = 0; ns < NST; ++ns) {
            int co = ns * 16 + lrow;
            bf16x8 b = *(const bf16x8*)&Wb[co * CIP + swz(co, kg)];
#pragma unroll
            for (int ms = 0; ms < 2; ++ms)
                acc[ms][ns] = __builtin_amdgcn_mfma_f32_16x16x32_bf16(
                    a[ms], b, acc[ms][ns], 0, 0, 0);
        }
    }
#pragma unroll
    for (int ms = 0; ms < 2; ++ms)
#pragma unroll
        for (int ns = 0; ns < NST; ++ns)
#pragma unroll
            for (int r = 0; r < 4; ++r) {
                int sg = swave + ms * 16 + kg * 4 + r;
                if (sg < SP_) {
                    int co = ns * 16 + lrow;
                    outT[((size_t)n * SP_ + sg) * NCO + co] = acc[ms][ns][r] + bias[co];
                }
            }
}

// ---------------- softmax over d, layout [n][s][112] (d contiguous) ----------
// one wave per point; lanes hold d=lane and d=lane+64 (lane<48)
__global__ __launch_bounds__(256) void softmax2_k(
    const float* __restrict__ lg, float* __restrict__ pr)
{
    const int p = blockIdx.x * 4 + (threadIdx.x >> 6);
    if (p >= NIMG * SP_) return;
    const int lane = threadIdx.x & 63;
    const float* lp = lg + (size_t)p * DCH;
    float v0 = lp[lane];
    float v1 = (lane < DCH - 64) ? lp[64 + lane] : -1e30f;
    float m = fmaxf(v0, v1);
#pragma unroll
    for (int o = 32; o; o >>= 1) m = fmaxf(m, __shfl_xor(m, o));
    float e0 = __expf(v0 - m);
    float e1 = (lane < DCH - 64) ? __expf(v1 - m) : 0.f;
    float s = e0 + e1;
#pragma unroll
    for (int o = 32; o; o >>= 1) s += __shfl_xor(s, o);
    const float inv = 1.f / s;
    float* pp = pr + (size_t)p * DCH;
    pp[lane] = e0 * inv;
    if (lane < DCH - 64) pp[64 + lane] = e1 * inv;
}

// ---------------- per-camera geometry constants (fp64, closed-form) ----------
__device__ __forceinline__ void inv4(const double* M, double* inv) {
    inv[0]  =  M[5]*M[10]*M[15] - M[5]*M[11]*M[14] - M[9]*M[6]*M[15] + M[9]*M[7]*M[14] + M[13]*M[6]*M[11] - M[13]*M[7]*M[10];
    inv[4]  = -M[4]*M[10]*M[15] + M[4]*M[11]*M[14] + M[8]*M[6]*M[15] - M[8]*M[7]*M[14] - M[12]*M[6]*M[11] + M[12]*M[7]*M[10];
    inv[8]  =  M[4]*M[9]*M[15]  - M[4]*M[11]*M[13] - M[8]*M[5]*M[15] + M[8]*M[7]*M[13] + M[12]*M[5]*M[11] - M[12]*M[7]*M[9];
    inv[12] = -M[4]*M[9]*M[14]  + M[4]*M[10]*M[13] + M[8]*M[5]*M[14] - M[8]*M[6]*M[13] - M[12]*M[5]*M[10] + M[12]*M[6]*M[9];
    inv[1]  = -M[1]*M[10]*M[15] + M[1]*M[11]*M[14] + M[9]*M[2]*M[15] - M[9]*M[3]*M[14] - M[13]*M[2]*M[11] + M[13]*M[3]*M[10];
    inv[5]  =  M[0]*M[10]*M[15] - M[0]*M[11]*M[14] - M[8]*M[2]*M[15] + M[8]*M[3]*M[14] + M[12]*M[2]*M[11] - M[12]*M[3]*M[10];
    inv[9]  = -M[0]*M[9]*M[15]  + M[0]*M[11]*M[13] + M[8]*M[1]*M[15] - M[8]*M[3]*M[13] - M[12]*M[1]*M[11] + M[12]*M[3]*M[9];
    inv[13] =  M[0]*M[9]*M[14]  - M[0]*M[10]*M[13] - M[8]*M[1]*M[14] + M[8]*M[2]*M[13] + M[12]*M[1]*M[10] - M[12]*M[2]*M[9];
    inv[2]  =  M[1]*M[6]*M[15]  - M[1]*M[7]*M[14]  - M[5]*M[2]*M[15] + M[5]*M[3]*M[14] + M[13]*M[2]*M[7]  - M[13]*M[3]*M[6];
    inv[6]  = -M[0]*M[6]*M[15]  + M[0]*M[7]*M[14]  + M[4]*M[2]*M[15] - M[4]*M[3]*M[14] - M[12]*M[2]*M[7]  + M[12]*M[3]*M[6];
    inv[10] =  M[0]*M[5]*M[15]  - M[0]*M[7]*M[13]  - M[4]*M[1]*M[15] + M[4]*M[3]*M[13] + M[12]*M[1]*M[7]  - M[12]*M[3]*M[5];
    inv[14] = -M[0]*M[5]*M[14]  + M[0]*M[6]*M[13]  + M[4]*M[1]*M[14] - M[4]*M[2]*M[13] - M[12]*M[1]*M[6]  + M[12]*M[2]*M[5];
    inv[3]  = -M[1]*M[6]*M[11]  + M[1]*M[7]*M[10]  + M[5]*M[2]*M[11] - M[5]*M[3]*M[10] - M[9]*M[2]*M[7]   + M[9]*M[3]*M[6];
    inv[7]  =  M[0]*M[6]*M[11]  - M[0]*M[7]*M[10]  - M[4]*M[2]*M[11] + M[4]*M[3]*M[10] + M[8]*M[2]*M[7]   - M[8]*M[3]*M[6];
    inv[11] = -M[0]*M[5]*M[11]  + M[0]*M[7]*M[9]   + M[4]*M[1]*M[11] - M[4]*M[3]*M[9]  - M[8]*M[1]*M[7]   + M[8]*M[3]*M[5];
    inv[15] =  M[0]*M[5]*M[10]  - M[0]*M[6]*M[9]   - M[4]*M[1]*M[10] + M[4]*M[2]*M[9]  + M[8]*M[1]*M[6]   - M[8]*M[2]*M[5];
    double det = M[0]*inv[0] + M[1]*inv[4] + M[2]*inv[8] + M[3]*inv[12];
    double id = 1.0 / det;
#pragma unroll
    for (int i = 0; i < 16; ++i) inv[i] *= id;
}

__global__ void geom_setup_k(const float* __restrict__ s2e, const float* __restrict__ intrin,
                             const float* __restrict__ ida, const float* __restrict__ bda,
                             double* __restrict__ gc)
{
    const int n = threadIdx.x;
    if (n >= NIMG) return;
    double M[16], Iv[16];
#pragma unroll
    for (int i = 0; i < 16; ++i) M[i] = (double)ida[n * 16 + i];
    inv4(M, Iv);
    double R[3][3], tv[3];
#pragma unroll
    for (int r = 0; r < 3; ++r) {
#pragma unroll
        for (int c = 0; c < 3; ++c) R[r][c] = Iv[r * 4 + c];
        tv[r] = Iv[r * 4 + 3];
    }
    double K[3][3];
#pragma unroll
    for (int r = 0; r < 3; ++r)
#pragma unroll
        for (int c = 0; c < 3; ++c) K[r][c] = (double)intrin[n * 16 + r * 4 + c];
    double det = K[0][0] * (K[1][1] * K[2][2] - K[1][2] * K[2][1])
               - K[0][1] * (K[1][0] * K[2][2] - K[1][2] * K[2][0])
               + K[0][2] * (K[1][0] * K[2][1] - K[1][1] * K[2][0]);
    double id = 1.0 / det;
    double Ki[3][3];
    Ki[0][0] = (K[1][1] * K[2][2] - K[1][2] * K[2][1]) * id;
    Ki[0][1] = (K[0][2] * K[2][1] - K[0][1] * K[2][2]) * id;
    Ki[0][2] = (K[0][1] * K[1][2] - K[0][2] * K[1][1]) * id;
    Ki[1][0] = (K[1][2] * K[2][0] - K[1][0] * K[2][2]) * id;
    Ki[1][1] = (K[0][0] * K[2][2] - K[0][2] * K[2][0]) * id;
    Ki[1][2] = (K[0][2] * K[1][0] - K[0][0] * K[1][2]) * id;
    Ki[2][0] = (K[1][0] * K[2][1] - K[1][1] * K[2][0]) * id;
    Ki[2][1] = (K[0][1] * K[2][0] - K[0][0] * K[2][1]) * id;
    Ki[2][2] = (K[0][0] * K[1][1] - K[0][1] * K[1][0]) * id;
    double A[3][3], bv[3];
#pragma unroll
    for (int r = 0; r < 3; ++r) {
#pragma unroll
        for (int c = 0; c < 3; ++c)
            A[r][c] = Ki[r][0] * R[0][c] + Ki[r][1] * R[1][c] + Ki[r][2] * R[2][c];
        bv[r] = Ki[r][0] * tv[0] + Ki[r][1] * tv[1] + Ki[r][2] * tv[2];
    }
    double* g = gc + n * 24;
#pragma unroll
    for (int r = 0; r < 3; ++r)
#pragma unroll
        for (int c = 0; c < 3; ++c) g[r * 3 + c] = A[r][c];
#pragma unroll
    for (int r = 0; r < 3; ++r) g[9 + r] = bv[r];
#pragma unroll
    for (int r = 0; r < 3; ++r)
#pragma unroll
        for (int c = 0; c < 4; ++c) {
            double acc = 0.0;
#pragma unroll
            for (int k = 0; k < 4; ++k)
                acc += (double)bda[r * 4 + k] * (double)s2e[n * 16 + k * 4 + c];
            g[12 + r * 4 + c] = acc;
        }
}

// ---------------- per-point voxel index + histogram (fused) ------------------
__global__ __launch_bounds__(256) void point_voxel_k(
    const double* __restrict__ gc, int* __restrict__ vidx, int* __restrict__ cnt)
{
    const int i = blockIdx.x * 256 + threadIdx.x;
    if (i >= NPTS) return;
    const int n = i / (DCH * SP_);
    int r = i - n * (DCH * SP_);
    const int di = r / SP_;
    const int s = r - di * SP_;
    const int h = s / FW_, w = s - h * FW_;
    const double* g = gc + n * 24;
    const double u  = (double)(float)((double)w * (703.0 / 43.0));
    const double v  = (double)(float)((double)h * 17.0);
    const double dd = (double)(float)(2.0 + (double)di * (56.0 / 111.0));
    const double rx = g[0] * u + g[1] * v + g[2] + g[9];
    const double ry = g[3] * u + g[4] * v + g[5] + g[10];
    const double rz = g[6] * u + g[7] * v + g[8] + g[11];
    const double px = rx * dd, py = ry * dd, pz = rz * dd;
    const double ex = g[12] * px + g[13] * py + g[14] * pz + g[15];
    const double ey = g[16] * px + g[17] * py + g[18] * pz + g[19];
    const double ez = g[20] * px + g[21] * py + g[22] * pz + g[23];
    const double vs_xy = 0.8, vs_z = 8.0;
    const double offx = (double)(float)(-51.2 + 0.4) - vs_xy * 0.5;
    const double offz = (double)(float)(-5.0 + 4.0) - vs_z * 0.5;
    const int gx = (int)((ex - offx) / vs_xy);
    const int gy = (int)((ey - offx) / vs_xy);
    const int gz = (int)((ez - offz) / vs_z);
    const bool ok = (gx >= 0 && gx < NXY && gy >= 0 && gy < NXY && gz == 0);
    const int vv = ok ? (gy * NXY + gx) : -1;
    vidx[i] = vv;
    if (vv >= 0) atomicAdd(&cnt[vv], 1);
}

// off has NVOX+1 entries; off[NVOX] = total valid points
__global__ void prefix_k(const int* __restrict__ cnt, int* __restrict__ off,
                         int* __restrict__ cur) {
    __shared__ int part[256];
    const int t = threadIdx.x;
    int s = 0;
    for (int j = 0; j < 64; ++j) s += cnt[t * 64 + j];
    part[t] = s;
    __syncthreads();
    if (t == 0) {
        int run = 0;
        for (int k = 0; k < 256; ++k) { int v = part[k]; part[k] = run; run += v; }
    }
    __syncthreads();
    int base = part[t];
    for (int j = 0; j < 64; ++j) {
        off[t * 64 + j] = base;
        cur[t * 64 + j] = base;
        base += cnt[t * 64 + j];
    }
    if (t == 255) off[NVOX] = base;
}

// fill packed entries: key = (v<<13) | (n*SP_+s), prob bits
// prob layout now [n][s][112]
__global__ void fill_k(const int* __restrict__ vidx, const float* __restrict__ prob,
                       int* __restrict__ cur, int2* __restrict__ pk) {
    int i = blockIdx.x * 256 + threadIdx.x;
    if (i >= NPTS) return;
    int v = vidx[i];
    if (v < 0) return;
    const int n = i / (DCH * SP_);
    int r = i - n * (DCH * SP_);
    const int di = r / SP_;
    const int s = r - di * SP_;
    int pos = atomicAdd(&cur[v], 1);
    pk[pos] = make_int2((v << 13) | (n * SP_ + s),
                        __float_as_int(prob[((size_t)n * SP_ + s) * DCH + di]));
}

// ---------------- gather: chunk-per-wave segmented reduction ------------------
__global__ __launch_bounds__(256) void gather2_k(
    const int2* __restrict__ pk, const int* __restrict__ off,
    const float* __restrict__ ctxT, float* __restrict__ accT)
{
    const int gtid = blockIdx.x * 256 + threadIdx.x;
    const int wid = gtid >> 6;
    const int lane = threadIdx.x & 63;
    const int total = off[NVOX];
    const int lo = wid * CHUNK;
    if (lo >= total) return;
    const int hi = min(lo + CHUNK, total);
    float a0 = 0.f, a1 = 0.f;
    int2 e = pk[lo];
    for (int k = lo; k < hi; ++k) {
        const int2 en = (k + 1 < hi) ? pk[k + 1] : make_int2(-1, 0);
        const float p = __int_as_float(e.y);
        const int ns = e.x & 8191;
        const float* cb = ctxT + (size_t)ns * CCTX;
        a0 = fmaf(p, cb[lane], a0);
        if (lane < CCTX - 64) a1 = fmaf(p, cb[64 + lane], a1);
        if ((en.x >> 13) != (e.x >> 13)) {         // wave-uniform flush
            float* ab = accT + (size_t)(e.x >> 13) * CCTX;
            atomicAdd(ab + lane, a0);
            if (lane < CCTX - 64) atomicAdd(ab + 64 + lane, a1);
            a0 = a1 = 0.f;
        }
        e = en;
    }
}

// ---------------- transpose accT [v][c] -> out [c][v] ------------------------
__global__ void transpose_out_k(const float* __restrict__ accT, float* __restrict__ out) {
    const int idx = blockIdx.x * 256 + threadIdx.x;
    if (idx >= CCTX * NVOX) return;
    const int c = idx >> 14;
    const int v = idx & 16383;
    out[idx] = accT[(size_t)v * CCTX + c];
}

// ---------------- workspace layout (float offsets) ---------------------------
#define O_WHI   512           // bf16 conv weights [9][512][512]: 1,179,648
#define O_XT0   1180160       // 1,474,560
#define O_XT1   2654720       // 1,474,560
#define O_XT2   4129280       // 1,474,560
#define O_WD2B  5603840       // 28,672 (bf16 112x512)
#define O_WC2B  5632512       // 20,480 (bf16 80x512)
#define O_DLG   5652992       // 473,088  [n][s][112]
#define O_DPR   6126080       // 473,088
#define O_CTX   6599168       // 337,920  [n][s][80]
#define O_PK    6937088       // 946,176 (int2 x 473,088)
#define O_VIX   7883264       // 473,088
#define O_CNT   8356352       // 16,384
#define O_OFF   8372736       // 16,400
#define O_CUR   8389136       // 16,384
#define O_ACC   8405520       // 1,310,720
// end: 9,716,240 floats = 38.9 MB

extern "C" void kernel_launch(void* const* d_in, const int* in_sizes, int n_in,
                              void* d_out, int out_size, void* d_ws, size_t ws_size,
                              hipStream_t stream)
{
    const float* src  = (const float*)d_in[0];
    const float* w_s1 = (const float*)d_in[1];
    const float* w_s2 = (const float*)d_in[2];
    const float* w_d1 = (const float*)d_in[3];
    const float* w_d2 = (const float*)d_in[4];
    const float* b_d  = (const float*)d_in[5];
    const float* w_c1 = (const float*)d_in[6];
    const float* w_c2 = (const float*)d_in[7];
    const float* b_c  = (const float*)d_in[8];
    const float* s2e  = (const float*)d_in[9];
    const float* intr = (const float*)d_in[10];
    const float* ida  = (const float*)d_in[11];
    const float* bda  = (const float*)d_in[12];

    double* gc = (double*)d_ws;
    float* ws   = (float*)d_ws;
    short* whi  = (short*)(ws + O_WHI);
    short* xt0  = (short*)(ws + O_XT0);
    short* xt1  = (short*)(ws + O_XT1);
    short* xt2  = (short*)(ws + O_XT2);
    short* wd2b = (short*)(ws + O_WD2B);
    short* wc2b = (short*)(ws + O_WC2B);
    float* dlog = ws + O_DLG;
    float* dprb = ws + O_DPR;
    float* ctxT = ws + O_CTX;
    int2*  pk   = (int2*)(ws + O_PK);
    int* vidx   = (int*)(ws + O_VIX);
    int* cnt    = (int*)(ws + O_CNT);
    int* offs   = (int*)(ws + O_OFF);
    int* cur    = (int*)(ws + O_CUR);
    float* accT = ws + O_ACC;
    float* out  = (float*)d_out;

    // zero xt0+xt1 (contiguous; provides pad borders). xt2 needs no zeroing
    // (its consumer reads only rows the d1 conv writes).
    zero_k<<<(2949120 / 4 + 255) / 256, 256, 0, stream>>>((float4*)xt0, 2949120 / 4);

    geom_setup_k<<<1, 64, 0, stream>>>(s2e, intr, ida, bda, gc);
    src_to_xt_k<<<(NIMG * SP_ * CIN + 255) / 256, 256, 0, stream>>>(src, xt0);

    dim3 cg(6, 8, NIMG);
    // s1: xt0 -> xt1
    wsplit_k<<<(CIN * CIN) / 256, 256, 0, stream>>>(w_s1, whi);
    conv3_k<<<cg, 128, 0, stream>>>(xt0, whi, xt1);
    // s2: xt1 -> xt0
    wsplit_k<<<(CIN * CIN) / 256, 256, 0, stream>>>(w_s2, whi);
    conv3_k<<<cg, 128, 0, stream>>>(xt1, whi, xt0);
    // d1: xt0 -> xt2
    wsplit_k<<<(CIN * CIN) / 256, 256, 0, stream>>>(w_d1, whi);
    conv3_k<<<cg, 128, 0, stream>>>(xt0, whi, xt2);
    // d2 gemm: xt2 -> dlog [n][s][112]; softmax -> dprb
    wsplit1_k<<<(DCH * CIN + 255) / 256, 256, 0, stream>>>(w_d2, wd2b, DCH * CIN);
    gemm1x1_k<DCH><<<dim3(6, 1, NIMG), 256, 0, stream>>>(xt2, wd2b, b_d, dlog);
    softmax2_k<<<(NIMG * SP_ + 3) / 4, 256, 0, stream>>>(dlog, dprb);

    // binning
    zero_k<<<(NVOX / 4 + 255) / 256, 256, 0, stream>>>((float4*)cnt, NVOX / 4);
    point_voxel_k<<<(NPTS + 255) / 256, 256, 0, stream>>>(gc, vidx, cnt);
    prefix_k<<<1, 256, 0, stream>>>(cnt, offs, cur);
    fill_k<<<(NPTS + 255) / 256, 256, 0, stream>>>(vidx, dprb, cur, pk);

    // c1: xt0 -> xt1 (xt1 free after s2; pads still zero)
    wsplit_k<<<(CIN * CIN) / 256, 256, 0, stream>>>(w_c1, whi);
    conv3_k<<<cg, 128, 0, stream>>>(xt0, whi, xt1);
    // c2 gemm: xt1 -> ctxT [n][s][80]
    wsplit1_k<<<(CCTX * CIN + 255) / 256, 256, 0, stream>>>(w_c2, wc2b, CCTX * CIN);
    gemm1x1_k<CCTX><<<dim3(6, 1, NIMG), 256, 0, stream>>>(xt1, wc2b, b_c, ctxT);

    // segmented-reduction gather
    zero_k<<<(1310720 / 4 + 255) / 256, 256, 0, stream>>>((float4*)accT, 1310720 / 4);
    {
        const int waves = (NPTS + CHUNK - 1) / CHUNK;
        const int blocks = (waves + 3) / 4;
        gather2_k<<<blocks, 256, 0, stream>>>(pk, offs, ctxT, accT);
    }
    transpose_out_k<<<(CCTX * NVOX + 255) / 256, 256, 0, stream>>>(accT, out);

    (void)in_sizes; (void)n_in; (void)out_size; (void)ws_size;
}

// Round 11
// 522.526 us; speedup vs baseline: 1.5118x; 1.5118x over previous
//
#include <hip/hip_runtime.h>

// LSS-FPN round 10: conv reverted to R8-proven 128sp x 32co config; d1+c1
// fused into one 2304-block dispatch; dual weight-convert kernels.
// Tail (gemm1x1 / softmax2 / binning / gather) kept from R9. WS ~43.6 MB.

#define FH_ 16
#define FW_ 44
#define SP_ 704
#define XSTR 960         // xt rows per image (incl. halo slack)
#define NIMG 6
#define CIN 512
#define DCH 112
#define CCTX 80
#define NXY 128
#define NVOX (NXY * NXY)
#define NPTS (NIMG * DCH * SP_)
#define CHUNK 64

#define WROWS 232        // LDS X window rows (128-px tile + 3x3 halo)
#define CIP 40           // padded LDS k-stride in shorts

typedef unsigned short u16;
typedef __attribute__((ext_vector_type(8))) short bf16x8;
typedef __attribute__((ext_vector_type(4))) float f32x4;

__device__ __forceinline__ float bf2f(u16 b) {
    union { unsigned u; float f; } v; v.u = ((unsigned)b) << 16; return v.f;
}
__device__ __forceinline__ u16 f2bf(float f) {
    union { float f; unsigned u; } v; v.f = f;
    unsigned r = v.u + 0x7fffu + ((v.u >> 16) & 1u);   // RTNE
    return (u16)(r >> 16);
}
__device__ __forceinline__ int spad_of(int s) {
    return (s / 44) * 46 + (s % 44) + 47;
}

// ---------------- zero fill ---------------------------------------------------
__global__ void zero_k(float4* __restrict__ p, long n4) {
    long i = (long)blockIdx.x * blockDim.x + threadIdx.x;
    if (i < n4) p[i] = make_float4(0.f, 0.f, 0.f, 0.f);
}

// ---------------- src fp32 [n][ci][704] -> xt bf16 [n][XSTR][512] -------------
__global__ void src_to_xt_k(const float* __restrict__ src, short* __restrict__ xt) {
    int e = blockIdx.x * 256 + threadIdx.x;
    if (e >= NIMG * SP_ * CIN) return;
    int ci = e & 511;
    int r = e >> 9;
    int s = r % SP_, n = r / SP_;
    float v = src[((size_t)n * CIN + ci) * SP_ + s];
    xt[((size_t)n * XSTR + spad_of(s)) * 512 + ci] = (short)f2bf(v);
}

// ---------------- weight convert: fp32 [co][ci][9] -> bf16 [t][co][ci] --------
__global__ void wsplit_k(const float* __restrict__ w, short* __restrict__ hi) {
    int e = blockIdx.x * 256 + threadIdx.x;
    if (e >= CIN * CIN) return;
    const float* wp = w + (size_t)e * 9;
#pragma unroll
    for (int t = 0; t < 9; ++t)
        hi[(size_t)t * (CIN * CIN) + e] = (short)f2bf(wp[t]);
}

// dual: converts two 3x3 weight tensors in one dispatch
__global__ void wsplit_dual_k(const float* __restrict__ w1, short* __restrict__ o1,
                              const float* __restrict__ w2, short* __restrict__ o2) {
    int i = blockIdx.x * 256 + threadIdx.x;
    if (i >= 2 * CIN * CIN) return;
    int e = i & (CIN * CIN - 1);
    const float* w = (i < CIN * CIN) ? w1 : w2;
    short* o = (i < CIN * CIN) ? o1 : o2;
    const float* wp = w + (size_t)e * 9;
#pragma unroll
    for (int t = 0; t < 9; ++t)
        o[(size_t)t * (CIN * CIN) + e] = (short)f2bf(wp[t]);
}

// dual 1x1 weights fp32 [co][ci] -> bf16
__global__ void wsplit1_dual_k(const float* __restrict__ wd, short* __restrict__ od,
                               const float* __restrict__ wc, short* __restrict__ oc) {
    int i = blockIdx.x * 256 + threadIdx.x;
    if (i < DCH * CIN) od[i] = (short)f2bf(wd[i]);
    else if (i < DCH * CIN + CCTX * CIN) {
        int j = i - DCH * CIN;
        oc[j] = (short)f2bf(wc[j]);
    }
}

// ---------------- conv3x3+relu body (R8-proven config) ------------------------
// 128sp x 32co tile, 256 thr = 4 waves stacked in M (each 32sp x 32co).
__device__ __forceinline__ void conv3_body(
    const short* __restrict__ xt, const short* __restrict__ wth,
    short* __restrict__ xout, int sblk, int co0, int n)
{
    __shared__ short Xs[WROWS * CIP];       // 18,560 B
    __shared__ short Wsh[9 * 32 * CIP];     // 23,040 B
    const int tid = threadIdx.x;
    const int s0 = sblk * 128;
    const int base = spad_of(s0) - 47;
    const int lane = tid & 63, wave = tid >> 6;
    const int kg = lane >> 4, lrow = lane & 15;

    int sloc[2];
#pragma unroll
    for (int ms = 0; ms < 2; ++ms)
        sloc[ms] = spad_of(s0 + wave * 32 + ms * 16 + lrow) - base;
    int bofs[2];
#pragma unroll
    for (int ns = 0; ns < 2; ++ns)
        bofs[ns] = (ns * 16 + lrow) * CIP + kg * 8;

    const f32x4 zero4 = {0.f, 0.f, 0.f, 0.f};
    f32x4 acc[2][2];
#pragma unroll
    for (int ms = 0; ms < 2; ++ms)
#pragma unroll
        for (int ns = 0; ns < 2; ++ns) acc[ms][ns] = zero4;

    const short* xb = xt + ((size_t)n * XSTR + base) * 512;

    for (int kc = 0; kc < 16; ++kc) {
        __syncthreads();
        // stage X window: 232 rows x 4 chunks = 928 tasks
#pragma unroll
        for (int it = 0; it < 4; ++it) {
            int q = it * 256 + tid;
            if (q < WROWS * 4) {
                int row = q >> 2, p = q & 3;
                *(bf16x8*)&Xs[row * CIP + p * 8] =
                    *(const bf16x8*)(xb + (size_t)row * 512 + kc * 32 + p * 8);
            }
        }
        // stage W: 9 taps x 32 co x 4 chunks = 1152 tasks
#pragma unroll
        for (int it = 0; it < 5; ++it) {
            int q = it * 256 + tid;
            if (q < 9 * 32 * 4) {
                int t = q >> 7, co = (q >> 2) & 31, p = q & 3;
                *(bf16x8*)&Wsh[(t * 32 + co) * CIP + p * 8] =
                    *(const bf16x8*)(wth + ((size_t)t * CIN + co0 + co) * CIN + kc * 32 + p * 8);
            }
        }
        __syncthreads();
        constexpr int OFF[9] = {-47, -46, -45, -1, 0, 1, 45, 46, 47};
#pragma unroll
        for (int t = 0; t < 9; ++t) {
            const int off = OFF[t];
            bf16x8 a0 = *(const bf16x8*)&Xs[(sloc[0] + off) * CIP + kg * 8];
            bf16x8 a1 = *(const bf16x8*)&Xs[(sloc[1] + off) * CIP + kg * 8];
#pragma unroll
            for (int ns = 0; ns < 2; ++ns) {
                bf16x8 b = *(const bf16x8*)&Wsh[t * 32 * CIP + bofs[ns]];
                acc[0][ns] = __builtin_amdgcn_mfma_f32_16x16x32_bf16(a0, b, acc[0][ns], 0, 0, 0);
                acc[1][ns] = __builtin_amdgcn_mfma_f32_16x16x32_bf16(a1, b, acc[1][ns], 0, 0, 0);
            }
        }
    }
    // epilogue: C row = kg*4+r (spatial), col = lrow (co); relu; bf16 store
#pragma unroll
    for (int ms = 0; ms < 2; ++ms)
#pragma unroll
        for (int ns = 0; ns < 2; ++ns)
#pragma unroll
            for (int r = 0; r < 4; ++r) {
                int sg = s0 + wave * 32 + ms * 16 + kg * 4 + r;
                if (sg < SP_) {
                    int co = co0 + ns * 16 + lrow;
                    float v = fmaxf(acc[ms][ns][r], 0.f);
                    xout[((size_t)n * XSTR + spad_of(sg)) * 512 + co] = (short)f2bf(v);
                }
            }
}

// single-layer conv: grid (6, 16, 6)
__global__ __launch_bounds__(256, 2) void conv3_k(
    const short* __restrict__ xt, const short* __restrict__ wth,
    short* __restrict__ xout)
{
    conv3_body(xt, wth, xout, blockIdx.x, blockIdx.y * 32, blockIdx.z);
}

// fused d1+c1: grid (6, 32, 6); y<16 -> layer A, else layer B
__global__ __launch_bounds__(256, 2) void conv3_dual_k(
    const short* __restrict__ xt,
    const short* __restrict__ wA, short* __restrict__ outA,
    const short* __restrict__ wB, short* __restrict__ outB)
{
    const int yy = blockIdx.y;
    const short* wth = (yy < 16) ? wA : wB;
    short* xout = (yy < 16) ? outA : outB;
    conv3_body(xt, wth, xout, blockIdx.x, (yy & 15) * 32, blockIdx.z);
}

// ---------------- 1x1 conv as GEMM: xt bf16 -> fp32 [n][s][NCO] ---------------
template <int NCO>
__global__ __launch_bounds__(256, 2) void gemm1x1_k(
    const short* __restrict__ xtin, const short* __restrict__ wb,
    const float* __restrict__ bias, float* __restrict__ outT)
{
    constexpr int NST = NCO / 16;
    __shared__ short Wb[NCO * CIP];
    const int tid = threadIdx.x;
    const int s0 = blockIdx.x * 128, n = blockIdx.z;
    const int lane = tid & 63, wave = tid >> 6;
    const int kg = lane >> 4, lrow = lane & 15;
    const int swave = s0 + wave * 32;

    int arow[2];
#pragma unroll
    for (int ms = 0; ms < 2; ++ms)
        arow[ms] = spad_of(swave + ms * 16 + lrow);

    const f32x4 zero4 = {0.f, 0.f, 0.f, 0.f};
    f32x4 acc[2][NST];
#pragma unroll
    for (int ms = 0; ms < 2; ++ms)
#pragma unroll
        for (int ns = 0; ns < NST; ++ns) acc[ms][ns] = zero4;

    const short* xb = xtin + (size_t)n * XSTR * 512;

    for (int kc = 0; kc < 16; ++kc) {
        __syncthreads();
#pragma unroll
        for (int it = 0; it < 2; ++it) {
            int q = it * 256 + tid;
            if (q < NCO * 4) {
                int co = q >> 2, p = q & 3;
                *(bf16x8*)&Wb[co * CIP + p * 8] =
                    *(const bf16x8*)(wb + (size_t)co * CIN + kc * 32 + p * 8);
            }
        }
        __syncthreads();
        bf16x8 a[2];
#pragma unroll
        for (int ms = 0; ms < 2; ++ms)
            a[ms] = *(const bf16x8*)(xb + (size_t)arow[ms] * 512 + kc * 32 + kg * 8);
#pragma unroll
        for (int ns = 0; ns < NST; ++ns) {
            int co = ns * 16 + lrow;
            bf16x8 b = *(const bf16x8*)&Wb[co * CIP + kg * 8];
#pragma unroll
            for (int ms = 0; ms < 2; ++ms)
                acc[ms][ns] = __builtin_amdgcn_mfma_f32_16x16x32_bf16(
                    a[ms], b, acc[ms][ns], 0, 0, 0);
        }
    }
#pragma unroll
    for (int ms = 0; ms < 2; ++ms)
#pragma unroll
        for (int ns = 0; ns < NST; ++ns)
#pragma unroll
            for (int r = 0; r < 4; ++r) {
                int sg = swave + ms * 16 + kg * 4 + r;
                if (sg < SP_) {
                    int co = ns * 16 + lrow;
                    outT[((size_t)n * SP_ + sg) * NCO + co] = acc[ms][ns][r] + bias[co];
                }
            }
}

// ---------------- softmax over d, layout [n][s][112] (d contiguous) ----------
__global__ __launch_bounds__(256) void softmax2_k(
    const float* __restrict__ lg, float* __restrict__ pr)
{
    const int p = blockIdx.x * 4 + (threadIdx.x >> 6);
    if (p >= NIMG * SP_) return;
    const int lane = threadIdx.x & 63;
    const float* lp = lg + (size_t)p * DCH;
    float v0 = lp[lane];
    float v1 = (lane < DCH - 64) ? lp[64 + lane] : -1e30f;
    float m = fmaxf(v0, v1);
#pragma unroll
    for (int o = 32; o; o >>= 1) m = fmaxf(m, __shfl_xor(m, o));
    float e0 = __expf(v0 - m);
    float e1 = (lane < DCH - 64) ? __expf(v1 - m) : 0.f;
    float s = e0 + e1;
#pragma unroll
    for (int o = 32; o; o >>= 1) s += __shfl_xor(s, o);
    const float inv = 1.f / s;
    float* pp = pr + (size_t)p * DCH;
    pp[lane] = e0 * inv;
    if (lane < DCH - 64) pp[64 + lane] = e1 * inv;
}

// ---------------- per-camera geometry constants (fp64, closed-form) ----------
__device__ __forceinline__ void inv4(const double* M, double* inv) {
    inv[0]  =  M[5]*M[10]*M[15] - M[5]*M[11]*M[14] - M[9]*M[6]*M[15] + M[9]*M[7]*M[14] + M[13]*M[6]*M[11] - M[13]*M[7]*M[10];
    inv[4]  = -M[4]*M[10]*M[15] + M[4]*M[11]*M[14] + M[8]*M[6]*M[15] - M[8]*M[7]*M[14] - M[12]*M[6]*M[11] + M[12]*M[7]*M[10];
    inv[8]  =  M[4]*M[9]*M[15]  - M[4]*M[11]*M[13] - M[8]*M[5]*M[15] + M[8]*M[7]*M[13] + M[12]*M[5]*M[11] - M[12]*M[7]*M[9];
    inv[12] = -M[4]*M[9]*M[14]  + M[4]*M[10]*M[13] + M[8]*M[5]*M[14] - M[8]*M[6]*M[13] - M[12]*M[5]*M[10] + M[12]*M[6]*M[9];
    inv[1]  = -M[1]*M[10]*M[15] + M[1]*M[11]*M[14] + M[9]*M[2]*M[15] - M[9]*M[3]*M[14] - M[13]*M[2]*M[11] + M[13]*M[3]*M[10];
    inv[5]  =  M[0]*M[10]*M[15] - M[0]*M[11]*M[14] - M[8]*M[2]*M[15] + M[8]*M[3]*M[14] + M[12]*M[2]*M[11] - M[12]*M[3]*M[10];
    inv[9]  = -M[0]*M[9]*M[15]  + M[0]*M[11]*M[13] + M[8]*M[1]*M[15] - M[8]*M[3]*M[13] - M[12]*M[1]*M[11] + M[12]*M[3]*M[9];
    inv[13] =  M[0]*M[9]*M[14]  - M[0]*M[10]*M[13] - M[8]*M[1]*M[14] + M[8]*M[2]*M[13] + M[12]*M[1]*M[10] - M[12]*M[2]*M[9];
    inv[2]  =  M[1]*M[6]*M[15]  - M[1]*M[7]*M[14]  - M[5]*M[2]*M[15] + M[5]*M[3]*M[14] + M[13]*M[2]*M[7]  - M[13]*M[3]*M[6];
    inv[6]  = -M[0]*M[6]*M[15]  + M[0]*M[7]*M[14]  + M[4]*M[2]*M[15] - M[4]*M[3]*M[14] - M[12]*M[2]*M[7]  + M[12]*M[3]*M[6];
    inv[10] =  M[0]*M[5]*M[15]  - M[0]*M[7]*M[13]  - M[4]*M[1]*M[15] + M[4]*M[3]*M[13] + M[12]*M[1]*M[7]  - M[12]*M[3]*M[5];
    inv[14] = -M[0]*M[5]*M[14]  + M[0]*M[6]*M[13]  + M[4]*M[1]*M[14] - M[4]*M[2]*M[13] - M[12]*M[1]*M[6]  + M[12]*M[2]*M[5];
    inv[3]  = -M[1]*M[6]*M[11]  + M[1]*M[7]*M[10]  + M[5]*M[2]*M[11] - M[5]*M[3]*M[10] - M[9]*M[2]*M[7]   + M[9]*M[3]*M[6];
    inv[7]  =  M[0]*M[6]*M[11]  - M[0]*M[7]*M[10]  - M[4]*M[2]*M[11] + M[4]*M[3]*M[10] + M[8]*M[2]*M[7]   - M[8]*M[3]*M[6];
    inv[11] = -M[0]*M[5]*M[11]  + M[0]*M[7]*M[9]   + M[4]*M[1]*M[11] - M[4]*M[3]*M[9]  - M[8]*M[1]*M[7]   + M[8]*M[3]*M[5];
    inv[15] =  M[0]*M[5]*M[10]  - M[0]*M[6]*M[9]   - M[4]*M[1]*M[10] + M[4]*M[2]*M[9]  + M[8]*M[1]*M[6]   - M[8]*M[2]*M[5];
    double det = M[0]*inv[0] + M[1]*inv[4] + M[2]*inv[8] + M[3]*inv[12];
    double id = 1.0 / det;
#pragma unroll
    for (int i = 0; i < 16; ++i) inv[i] *= id;
}

__global__ void geom_setup_k(const float* __restrict__ s2e, const float* __restrict__ intrin,
                             const float* __restrict__ ida, const float* __restrict__ bda,
                             double* __restrict__ gc)
{
    const int n = threadIdx.x;
    if (n >= NIMG) return;
    double M[16], Iv[16];
#pragma unroll
    for (int i = 0; i < 16; ++i) M[i] = (double)ida[n * 16 + i];
    inv4(M, Iv);
    double R[3][3], tv[3];
#pragma unroll
    for (int r = 0; r < 3; ++r) {
#pragma unroll
        for (int c = 0; c < 3; ++c) R[r][c] = Iv[r * 4 + c];
        tv[r] = Iv[r * 4 + 3];
    }
    double K[3][3];
#pragma unroll
    for (int r = 0; r < 3; ++r)
#pragma unroll
        for (int c = 0; c < 3; ++c) K[r][c] = (double)intrin[n * 16 + r * 4 + c];
    double det = K[0][0] * (K[1][1] * K[2][2] - K[1][2] * K[2][1])
               - K[0][1] * (K[1][0] * K[2][2] - K[1][2] * K[2][0])
               + K[0][2] * (K[1][0] * K[2][1] - K[1][1] * K[2][0]);
    double id = 1.0 / det;
    double Ki[3][3];
    Ki[0][0] = (K[1][1] * K[2][2] - K[1][2] * K[2][1]) * id;
    Ki[0][1] = (K[0][2] * K[2][1] - K[0][1] * K[2][2]) * id;
    Ki[0][2] = (K[0][1] * K[1][2] - K[0][2] * K[1][1]) * id;
    Ki[1][0] = (K[1][2] * K[2][0] - K[1][0] * K[2][2]) * id;
    Ki[1][1] = (K[0][0] * K[2][2] - K[0][2] * K[2][0]) * id;
    Ki[1][2] = (K[0][2] * K[1][0] - K[0][0] * K[1][2]) * id;
    Ki[2][0] = (K[1][0] * K[2][1] - K[1][1] * K[2][0]) * id;
    Ki[2][1] = (K[0][1] * K[2][0] - K[0][0] * K[2][1]) * id;
    Ki[2][2] = (K[0][0] * K[1][1] - K[0][1] * K[1][0]) * id;
    double A[3][3], bv[3];
#pragma unroll
    for (int r = 0; r < 3; ++r) {
#pragma unroll
        for (int c = 0; c < 3; ++c)
            A[r][c] = Ki[r][0] * R[0][c] + Ki[r][1] * R[1][c] + Ki[r][2] * R[2][c];
        bv[r] = Ki[r][0] * tv[0] + Ki[r][1] * tv[1] + Ki[r][2] * tv[2];
    }
    double* g = gc + n * 24;
#pragma unroll
    for (int r = 0; r < 3; ++r)
#pragma unroll
        for (int c = 0; c < 3; ++c) g[r * 3 + c] = A[r][c];
#pragma unroll
    for (int r = 0; r < 3; ++r) g[9 + r] = bv[r];
#pragma unroll
    for (int r = 0; r < 3; ++r)
#pragma unroll
        for (int c = 0; c < 4; ++c) {
            double acc = 0.0;
#pragma unroll
            for (int k = 0; k < 4; ++k)
                acc += (double)bda[r * 4 + k] * (double)s2e[n * 16 + k * 4 + c];
            g[12 + r * 4 + c] = acc;
        }
}

// ---------------- per-point voxel index + histogram (fused) ------------------
__global__ __launch_bounds__(256) void point_voxel_k(
    const double* __restrict__ gc, int* __restrict__ vidx, int* __restrict__ cnt)
{
    const int i = blockIdx.x * 256 + threadIdx.x;
    if (i >= NPTS) return;
    const int n = i / (DCH * SP_);
    int r = i - n * (DCH * SP_);
    const int di = r / SP_;
    const int s = r - di * SP_;
    const int h = s / FW_, w = s - h * FW_;
    const double* g = gc + n * 24;
    const double u  = (double)(float)((double)w * (703.0 / 43.0));
    const double v  = (double)(float)((double)h * 17.0);
    const double dd = (double)(float)(2.0 + (double)di * (56.0 / 111.0));
    const double rx = g[0] * u + g[1] * v + g[2] + g[9];
    const double ry = g[3] * u + g[4] * v + g[5] + g[10];
    const double rz = g[6] * u + g[7] * v + g[8] + g[11];
    const double px = rx * dd, py = ry * dd, pz = rz * dd;
    const double ex = g[12] * px + g[13] * py + g[14] * pz + g[15];
    const double ey = g[16] * px + g[17] * py + g[18] * pz + g[19];
    const double ez = g[20] * px + g[21] * py + g[22] * pz + g[23];
    const double vs_xy = 0.8, vs_z = 8.0;
    const double offx = (double)(float)(-51.2 + 0.4) - vs_xy * 0.5;
    const double offz = (double)(float)(-5.0 + 4.0) - vs_z * 0.5;
    const int gx = (int)((ex - offx) / vs_xy);
    const int gy = (int)((ey - offx) / vs_xy);
    const int gz = (int)((ez - offz) / vs_z);
    const bool ok = (gx >= 0 && gx < NXY && gy >= 0 && gy < NXY && gz == 0);
    const int vv = ok ? (gy * NXY + gx) : -1;
    vidx[i] = vv;
    if (vv >= 0) atomicAdd(&cnt[vv], 1);
}

// off has NVOX+1 entries; off[NVOX] = total valid points
__global__ void prefix_k(const int* __restrict__ cnt, int* __restrict__ off,
                         int* __restrict__ cur) {
    __shared__ int part[256];
    const int t = threadIdx.x;
    int s = 0;
    for (int j = 0; j < 64; ++j) s += cnt[t * 64 + j];
    part[t] = s;
    __syncthreads();
    if (t == 0) {
        int run = 0;
        for (int k = 0; k < 256; ++k) { int v = part[k]; part[k] = run; run += v; }
    }
    __syncthreads();
    int base = part[t];
    for (int j = 0; j < 64; ++j) {
        off[t * 64 + j] = base;
        cur[t * 64 + j] = base;
        base += cnt[t * 64 + j];
    }
    if (t == 255) off[NVOX] = base;
}

// fill packed entries: key = (v<<13) | (n*SP_+s), prob bits; prob [n][s][112]
__global__ void fill_k(const int* __restrict__ vidx, const float* __restrict__ prob,
                       int* __restrict__ cur, int2* __restrict__ pk) {
    int i = blockIdx.x * 256 + threadIdx.x;
    if (i >= NPTS) return;
    int v = vidx[i];
    if (v < 0) return;
    const int n = i / (DCH * SP_);
    int r = i - n * (DCH * SP_);
    const int di = r / SP_;
    const int s = r - di * SP_;
    int pos = atomicAdd(&cur[v], 1);
    pk[pos] = make_int2((v << 13) | (n * SP_ + s),
                        __float_as_int(prob[((size_t)n * SP_ + s) * DCH + di]));
}

// ---------------- gather: chunk-per-wave segmented reduction ------------------
__global__ __launch_bounds__(256) void gather2_k(
    const int2* __restrict__ pk, const int* __restrict__ off,
    const float* __restrict__ ctxT, float* __restrict__ accT)
{
    const int gtid = blockIdx.x * 256 + threadIdx.x;
    const int wid = gtid >> 6;
    const int lane = threadIdx.x & 63;
    const int total = off[NVOX];
    const int lo = wid * CHUNK;
    if (lo >= total) return;
    const int hi = min(lo + CHUNK, total);
    float a0 = 0.f, a1 = 0.f;
    int2 e = pk[lo];
    for (int k = lo; k < hi; ++k) {
        const int2 en = (k + 1 < hi) ? pk[k + 1] : make_int2(-1, 0);
        const float p = __int_as_float(e.y);
        const int ns = e.x & 8191;
        const float* cb = ctxT + (size_t)ns * CCTX;
        a0 = fmaf(p, cb[lane], a0);
        if (lane < CCTX - 64) a1 = fmaf(p, cb[64 + lane], a1);
        if ((en.x >> 13) != (e.x >> 13)) {         // wave-uniform flush
            float* ab = accT + (size_t)(e.x >> 13) * CCTX;
            atomicAdd(ab + lane, a0);
            if (lane < CCTX - 64) atomicAdd(ab + 64 + lane, a1);
            a0 = a1 = 0.f;
        }
        e = en;
    }
}

// ---------------- transpose accT [v][c] -> out [c][v] ------------------------
__global__ void transpose_out_k(const float* __restrict__ accT, float* __restrict__ out) {
    const int idx = blockIdx.x * 256 + threadIdx.x;
    if (idx >= CCTX * NVOX) return;
    const int c = idx >> 14;
    const int v = idx & 16383;
    out[idx] = accT[(size_t)v * CCTX + c];
}

// ---------------- workspace layout (float offsets) ---------------------------
#define O_WHIA  512           // bf16 conv weights A [9][512][512]: 1,179,648
#define O_WHIB  1180160       // bf16 conv weights B: 1,179,648
#define O_XT0   2359808       // 1,474,560
#define O_XT1   3834368       // 1,474,560
#define O_XT2   5308928       // 1,474,560
#define O_WD2B  6783488       // 28,672 (bf16 112x512)
#define O_WC2B  6812160       // 20,480 (bf16 80x512)
#define O_DLG   6832640       // 473,088  [n][s][112]
#define O_DPR   7305728       // 473,088
#define O_CTX   7778816       // 337,920  [n][s][80]
#define O_PK    8116736       // 946,176 (int2 x 473,088)
#define O_VIX   9062912       // 473,088
#define O_CNT   9536000       // 16,384
#define O_OFF   9552384       // 16,400
#define O_CUR   9568784       // 16,384
#define O_ACC   9585168       // 1,310,720
// end: 10,895,888 floats = 43.6 MB

extern "C" void kernel_launch(void* const* d_in, const int* in_sizes, int n_in,
                              void* d_out, int out_size, void* d_ws, size_t ws_size,
                              hipStream_t stream)
{
    const float* src  = (const float*)d_in[0];
    const float* w_s1 = (const float*)d_in[1];
    const float* w_s2 = (const float*)d_in[2];
    const float* w_d1 = (const float*)d_in[3];
    const float* w_d2 = (const float*)d_in[4];
    const float* b_d  = (const float*)d_in[5];
    const float* w_c1 = (const float*)d_in[6];
    const float* w_c2 = (const float*)d_in[7];
    const float* b_c  = (const float*)d_in[8];
    const float* s2e  = (const float*)d_in[9];
    const float* intr = (const float*)d_in[10];
    const float* ida  = (const float*)d_in[11];
    const float* bda  = (const float*)d_in[12];

    double* gc = (double*)d_ws;
    float* ws   = (float*)d_ws;
    short* whiA = (short*)(ws + O_WHIA);
    short* whiB = (short*)(ws + O_WHIB);
    short* xt0  = (short*)(ws + O_XT0);
    short* xt1  = (short*)(ws + O_XT1);
    short* xt2  = (short*)(ws + O_XT2);
    short* wd2b = (short*)(ws + O_WD2B);
    short* wc2b = (short*)(ws + O_WC2B);
    float* dlog = ws + O_DLG;
    float* dprb = ws + O_DPR;
    float* ctxT = ws + O_CTX;
    int2*  pk   = (int2*)(ws + O_PK);
    int* vidx   = (int*)(ws + O_VIX);
    int* cnt    = (int*)(ws + O_CNT);
    int* offs   = (int*)(ws + O_OFF);
    int* cur    = (int*)(ws + O_CUR);
    float* accT = ws + O_ACC;
    float* out  = (float*)d_out;

    // zero xt0+xt1 (contiguous; provides pad borders). xt2 rows fully written
    // by d1 before being read -> no zeroing needed.
    zero_k<<<(2949120 / 4 + 255) / 256, 256, 0, stream>>>((float4*)xt0, 2949120 / 4);

    geom_setup_k<<<1, 64, 0, stream>>>(s2e, intr, ida, bda, gc);
    src_to_xt_k<<<(NIMG * SP_ * CIN + 255) / 256, 256, 0, stream>>>(src, xt0);

    dim3 cg(6, 16, NIMG);
    // s1: xt0 -> xt1
    wsplit_k<<<(CIN * CIN) / 256, 256, 0, stream>>>(w_s1, whiA);
    conv3_k<<<cg, 256, 0, stream>>>(xt0, whiA, xt1);
    // s2: xt1 -> xt0
    wsplit_k<<<(CIN * CIN) / 256, 256, 0, stream>>>(w_s2, whiA);
    conv3_k<<<cg, 256, 0, stream>>>(xt1, whiA, xt0);
    // d1 + c1 fused: xt0 -> xt2 (depth branch), xt0 -> xt1 (context branch)
    wsplit_dual_k<<<(2 * CIN * CIN) / 256, 256, 0, stream>>>(w_d1, whiA, w_c1, whiB);
    conv3_dual_k<<<dim3(6, 32, NIMG), 256, 0, stream>>>(xt0, whiA, xt2, whiB, xt1);

    // 1x1 weights (both) in one dispatch
    wsplit1_dual_k<<<((DCH + CCTX) * CIN + 255) / 256, 256, 0, stream>>>(w_d2, wd2b, w_c2, wc2b);
    // d2 gemm: xt2 -> dlog [n][s][112]; softmax -> dprb
    gemm1x1_k<DCH><<<dim3(6, 1, NIMG), 256, 0, stream>>>(xt2, wd2b, b_d, dlog);
    softmax2_k<<<(NIMG * SP_ + 3) / 4, 256, 0, stream>>>(dlog, dprb);
    // c2 gemm: xt1 -> ctxT [n][s][80]
    gemm1x1_k<CCTX><<<dim3(6, 1, NIMG), 256, 0, stream>>>(xt1, wc2b, b_c, ctxT);

    // binning
    zero_k<<<(NVOX / 4 + 255) / 256, 256, 0, stream>>>((float4*)cnt, NVOX / 4);
    point_voxel_k<<<(NPTS + 255) / 256, 256, 0, stream>>>(gc, vidx, cnt);
    prefix_k<<<1, 256, 0, stream>>>(cnt, offs, cur);
    fill_k<<<(NPTS + 255) / 256, 256, 0, stream>>>(vidx, dprb, cur, pk);

    // segmented-reduction gather
    zero_k<<<(1310720 / 4 + 255) / 256, 256, 0, stream>>>((float4*)accT, 1310720 / 4);
    {
        const int waves = (NPTS + CHUNK - 1) / CHUNK;
        const int blocks = (waves + 3) / 4;
        gather2_k<<<blocks, 256, 0, stream>>>(pk, offs, ctxT, accT);
    }
    transpose_out_k<<<(CCTX * NVOX + 255) / 256, 256, 0, stream>>>(accT, out);

    (void)in_sizes; (void)n_in; (void)out_size; (void)ws_size;
}